// Round 7
// baseline (178.282 us; speedup 1.0000x reference)
//
#include <hip/hip_runtime.h>

#define MAX_ITEMS 100000
constexpr int B = 4096;
constexpr int D = 512;
constexpr long long ACT_ELEMS  = (long long)B * D;               // 2097152
constexpr long long HIST_ELEMS = (long long)(MAX_ITEMS + 1) * D; // 51200512
// d_out layout: [0, ACT) activations, [ACT] loss, [ACT+1, ACT+1+HIST) new_history.

typedef float f32x4 __attribute__((ext_vector_type(4)));

// ---------------------------------------------------------------------------
// Kernel: one wave per sample. NT-stores the act passthrough, gathers the old
// row from the ORIGINAL history input, wave-reduces squared diff -> partial[s],
// atomicAdd-scatters the EMA update into new_history (duplicates accumulate).
// Runs after the history memcpy in stream order.
// ---------------------------------------------------------------------------
__global__ void update_kernel(const float* __restrict__ act,
                              const float* __restrict__ hist,
                              const int* __restrict__ samples,
                              float* __restrict__ out,
                              float* __restrict__ partial) {
    const int s    = blockIdx.x;
    const int lane = threadIdx.x; // 0..63

    const f32x4* __restrict__ arow =
        reinterpret_cast<const f32x4*>(act + (long long)s * D);
    f32x4* __restrict__ aout = reinterpret_cast<f32x4*>(out + (long long)s * D);
    const f32x4 a0 = arow[lane];
    const f32x4 a1 = arow[lane + 64];
    __builtin_nontemporal_store(a0, aout + lane);
    __builtin_nontemporal_store(a1, aout + lane + 64);

    const int id = samples[s];
    const bool active = (id > 0) && (id < MAX_ITEMS);

    float sumsq = 0.0f;
    if (active) {
        const f32x4* __restrict__ orow =
            reinterpret_cast<const f32x4*>(hist + (long long)id * D);
        float* __restrict__ newh = out + ACT_ELEMS + 1 + (long long)id * D;
        const f32x4 o0 = orow[lane];
        const f32x4 o1 = orow[lane + 64];
        {
            const float dx = a0.x - o0.x, dy = a0.y - o0.y;
            const float dz = a0.z - o0.z, dw = a0.w - o0.w;
            sumsq += dx * dx + dy * dy + dz * dz + dw * dw;
            const int e = lane * 4;
            atomicAdd(newh + e + 0, 0.1f * dx);
            atomicAdd(newh + e + 1, 0.1f * dy);
            atomicAdd(newh + e + 2, 0.1f * dz);
            atomicAdd(newh + e + 3, 0.1f * dw);
        }
        {
            const float dx = a1.x - o1.x, dy = a1.y - o1.y;
            const float dz = a1.z - o1.z, dw = a1.w - o1.w;
            sumsq += dx * dx + dy * dy + dz * dz + dw * dw;
            const int e = (lane + 64) * 4;
            atomicAdd(newh + e + 0, 0.1f * dx);
            atomicAdd(newh + e + 1, 0.1f * dy);
            atomicAdd(newh + e + 2, 0.1f * dz);
            atomicAdd(newh + e + 3, 0.1f * dw);
        }
    }
    #pragma unroll
    for (int off = 32; off; off >>= 1)
        sumsq += __shfl_down(sumsq, off);
    if (lane == 0) partial[s] = sumsq; // masked rows contribute exactly 0
}

// ---------------------------------------------------------------------------
// Deterministic single-block reduction of 4096 partials -> loss.
// ---------------------------------------------------------------------------
__global__ void loss_kernel(const float* __restrict__ partial,
                            const int* __restrict__ iters,
                            float* __restrict__ out) {
    __shared__ float sm[256];
    const int t = threadIdx.x;
    float s = 0.0f;
    for (int i = t; i < B; i += 256) s += partial[i];
    sm[t] = s;
    __syncthreads();
    #pragma unroll
    for (int w = 128; w; w >>= 1) {
        if (t < w) sm[t] += sm[t + w];
        __syncthreads();
    }
    if (t == 0) {
        const float it = (float)iters[0];
        const float wr = (float)(1.0 / 1000.0)   * it;
        const float cr = (float)(1.0 / 100000.0) * it;
        const float weight = 0.1f * wr / (1.0f + wr) / (1.0f + cr);
        out[ACT_ELEMS] = (sm[0] / (float)D / (float)B) * weight;
    }
}

extern "C" void kernel_launch(void* const* d_in, const int* in_sizes, int n_in,
                              void* d_out, int out_size, void* d_ws, size_t ws_size,
                              hipStream_t stream) {
    const float* act     = (const float*)d_in[0];
    const float* hist    = (const float*)d_in[1];
    const int*   samples = (const int*)d_in[2];
    const int*   iters   = (const int*)d_in[3];
    float* out     = (float*)d_out;
    float* partial = (float*)d_ws; // B*4 = 16 KiB scratch

    // History copy via the runtime's optimized D2D path (allowed in graph
    // capture per harness contract). Handles the 4B-misaligned dst natively.
    hipMemcpyAsync(out + ACT_ELEMS + 1, hist,
                   (size_t)HIST_ELEMS * sizeof(float),
                   hipMemcpyDeviceToDevice, stream);

    update_kernel<<<B, 64, 0, stream>>>(act, hist, samples, out, partial);
    loss_kernel<<<1, 256, 0, stream>>>(partial, iters, out);
}

// Round 8
// 131.022 us; speedup vs baseline: 1.3607x; 1.3607x over previous
//
#include <hip/hip_runtime.h>

#define MAX_ITEMS 100000
constexpr int B = 4096;
constexpr int D = 512;
constexpr long long ACT_ELEMS  = (long long)B * D;               // 2097152
constexpr long long HIST_ELEMS = (long long)(MAX_ITEMS + 1) * D; // 51200512
constexpr long long NG = (HIST_ELEMS - 3) / 4; // 12800127 dst-aligned float4 groups
// d_out layout: [0, ACT) activations, [ACT] loss, [ACT+1, ACT+1+HIST) new_history.
// outh = out + ACT+1 (4B-aligned); outh+3 IS 16B-aligned.

typedef float f32x4 __attribute__((ext_vector_type(4)));

// Streaming store: system-scope, non-temporal (sc0 sc1 nt). Goal: avoid
// L3 (MALL) write-allocation so the 210 MB/replay write stream stops
// evicting hist (205 MB) from the 256 MB L3. Plain `nt` (the builtin)
// did NOT change FETCH_SIZE (R3: 107 MB vs R6: 100 MB).
__device__ __forceinline__ void stream_store_x4(float* p, f32x4 v) {
    asm volatile("global_store_dwordx4 %0, %1, off sc0 sc1 nt"
                 :: "v"(p), "v"(v) : "memory");
}

// ---------------------------------------------------------------------------
// Kernel 1: history -> out[ACT+1..). dwordx4 both sides; dst group g =
// {src[g].w, src[g+1].xyz} realigned in-register via __shfl_down; lane 63
// patches with 3 scalar loads. Bulk stores use the streaming encoding.
// ---------------------------------------------------------------------------
template <int KU>
__global__ void copy_hist_kernel(const float* __restrict__ hist,
                                 float* __restrict__ out) {
    float* __restrict__ outh = out + ACT_ELEMS + 1;
    const float4* __restrict__ src = reinterpret_cast<const float4*>(hist);
    const int lane = threadIdx.x & 63;
    const long long chunk = (long long)blockDim.x * KU;

    for (long long c = blockIdx.x; c * chunk < NG; c += gridDim.x) {
        const long long g0 = c * chunk + threadIdx.x;
        float4 v[KU];
        #pragma unroll
        for (int k = 0; k < KU; ++k) {
            const long long g = g0 + (long long)k * blockDim.x;
            if (g <= NG) v[k] = src[g];   // group NG is valid src memory
        }
        #pragma unroll
        for (int k = 0; k < KU; ++k) {
            const long long g = g0 + (long long)k * blockDim.x;
            const float nx = __shfl_down(v[k].x, 1);
            const float ny = __shfl_down(v[k].y, 1);
            const float nz = __shfl_down(v[k].z, 1);
            if (g < NG) {
                f32x4 w;
                w.x = v[k].w; w.y = nx; w.z = ny; w.w = nz;
                if (lane == 63) { // g+1 lives in the next wave: patch scalar
                    w.y = hist[4 * (g + 1) + 0];
                    w.z = hist[4 * (g + 1) + 1];
                    w.w = hist[4 * (g + 1) + 2];
                }
                stream_store_x4(outh + 3 + 4 * g, w);
            }
        }
    }
    if (blockIdx.x == 0 && threadIdx.x == 0) {
        __builtin_nontemporal_store(hist[0], outh + 0);
        __builtin_nontemporal_store(hist[1], outh + 1);
        __builtin_nontemporal_store(hist[2], outh + 2);
        __builtin_nontemporal_store(hist[HIST_ELEMS - 1], outh + HIST_ELEMS - 1);
    }
}

// ---------------------------------------------------------------------------
// Kernel 2: one wave per sample. Streams the act passthrough, gathers the old
// row from the ORIGINAL history input, wave-reduces squared diff -> partial[s],
// atomicAdd-scatters the EMA update (duplicates accumulate). Runs after
// copy_hist in stream order.
// ---------------------------------------------------------------------------
__global__ void update_kernel(const float* __restrict__ act,
                              const float* __restrict__ hist,
                              const int* __restrict__ samples,
                              float* __restrict__ out,
                              float* __restrict__ partial) {
    const int s    = blockIdx.x;
    const int lane = threadIdx.x; // 0..63

    const f32x4* __restrict__ arow =
        reinterpret_cast<const f32x4*>(act + (long long)s * D);
    float* __restrict__ aoutf = out + (long long)s * D;
    const f32x4 a0 = arow[lane];
    const f32x4 a1 = arow[lane + 64];
    stream_store_x4(aoutf + lane * 4, a0);
    stream_store_x4(aoutf + (lane + 64) * 4, a1);

    const int id = samples[s];
    const bool active = (id > 0) && (id < MAX_ITEMS);

    float sumsq = 0.0f;
    if (active) {
        const f32x4* __restrict__ orow =
            reinterpret_cast<const f32x4*>(hist + (long long)id * D);
        float* __restrict__ newh = out + ACT_ELEMS + 1 + (long long)id * D;
        const f32x4 o0 = orow[lane];
        const f32x4 o1 = orow[lane + 64];
        {
            const float dx = a0.x - o0.x, dy = a0.y - o0.y;
            const float dz = a0.z - o0.z, dw = a0.w - o0.w;
            sumsq += dx * dx + dy * dy + dz * dz + dw * dw;
            const int e = lane * 4;
            atomicAdd(newh + e + 0, 0.1f * dx);
            atomicAdd(newh + e + 1, 0.1f * dy);
            atomicAdd(newh + e + 2, 0.1f * dz);
            atomicAdd(newh + e + 3, 0.1f * dw);
        }
        {
            const float dx = a1.x - o1.x, dy = a1.y - o1.y;
            const float dz = a1.z - o1.z, dw = a1.w - o1.w;
            sumsq += dx * dx + dy * dy + dz * dz + dw * dw;
            const int e = (lane + 64) * 4;
            atomicAdd(newh + e + 0, 0.1f * dx);
            atomicAdd(newh + e + 1, 0.1f * dy);
            atomicAdd(newh + e + 2, 0.1f * dz);
            atomicAdd(newh + e + 3, 0.1f * dw);
        }
    }
    #pragma unroll
    for (int off = 32; off; off >>= 1)
        sumsq += __shfl_down(sumsq, off);
    if (lane == 0) partial[s] = sumsq; // masked rows contribute exactly 0
}

// ---------------------------------------------------------------------------
// Kernel 3: deterministic single-block reduction of 4096 partials -> loss.
// ---------------------------------------------------------------------------
__global__ void loss_kernel(const float* __restrict__ partial,
                            const int* __restrict__ iters,
                            float* __restrict__ out) {
    __shared__ float sm[256];
    const int t = threadIdx.x;
    float s = 0.0f;
    for (int i = t; i < B; i += 256) s += partial[i];
    sm[t] = s;
    __syncthreads();
    #pragma unroll
    for (int w = 128; w; w >>= 1) {
        if (t < w) sm[t] += sm[t + w];
        __syncthreads();
    }
    if (t == 0) {
        const float it = (float)iters[0];
        const float wr = (float)(1.0 / 1000.0)   * it;
        const float cr = (float)(1.0 / 100000.0) * it;
        const float weight = 0.1f * wr / (1.0f + wr) / (1.0f + cr);
        out[ACT_ELEMS] = (sm[0] / (float)D / (float)B) * weight;
    }
}

extern "C" void kernel_launch(void* const* d_in, const int* in_sizes, int n_in,
                              void* d_out, int out_size, void* d_ws, size_t ws_size,
                              hipStream_t stream) {
    const float* act     = (const float*)d_in[0];
    const float* hist    = (const float*)d_in[1];
    const int*   samples = (const int*)d_in[2];
    const int*   iters   = (const int*)d_in[3];
    float* out     = (float*)d_out;
    float* partial = (float*)d_ws; // B*4 = 16 KiB scratch

    copy_hist_kernel<8><<<2048, 256, 0, stream>>>(hist, out);
    update_kernel<<<B, 64, 0, stream>>>(act, hist, samples, out, partial);
    loss_kernel<<<1, 256, 0, stream>>>(partial, iters, out);
}

// Round 9
// 124.855 us; speedup vs baseline: 1.4279x; 1.0494x over previous
//
#include <hip/hip_runtime.h>

#define MAX_ITEMS 100000
constexpr int B = 4096;
constexpr int D = 512;
constexpr long long ACT_ELEMS  = (long long)B * D;               // 2097152
constexpr long long HIST_ELEMS = (long long)(MAX_ITEMS + 1) * D; // 51200512
constexpr long long NG = (HIST_ELEMS - 3) / 4; // 12800127 dst-aligned float4 groups
// d_out layout: [0, ACT) activations, [ACT] loss, [ACT+1, ACT+1+HIST) new_history.
// outh = out + ACT+1 (4B-aligned); outh+3 IS 16B-aligned.

typedef float f32x4 __attribute__((ext_vector_type(4)));

// ---------------------------------------------------------------------------
// Kernel 1: history -> out[ACT+1..). dwordx4 both sides; dst group g =
// {src[g].w, src[g+1].xyz} realigned in-register via __shfl_down; lane 63
// patches with 3 scalar loads.
//   loads : NON-TEMPORAL (no L3 allocate) -> hist never half-caches, so the
//           per-replay read is a contiguous 100%-miss HBM stream instead of
//           a fragmented 50%-miss one (R6/R8: FETCH pinned at ~100MB).
//   stores: __builtin_nontemporal_store (R6-proven best; sc0sc1 asm was -20%).
// ---------------------------------------------------------------------------
template <int KU>
__global__ void copy_hist_kernel(const float* __restrict__ hist,
                                 float* __restrict__ out) {
    float* __restrict__ outh = out + ACT_ELEMS + 1;
    const f32x4* __restrict__ src = reinterpret_cast<const f32x4*>(hist);
    const int lane = threadIdx.x & 63;
    const long long chunk = (long long)blockDim.x * KU;

    for (long long c = blockIdx.x; c * chunk < NG; c += gridDim.x) {
        const long long g0 = c * chunk + threadIdx.x;
        f32x4 v[KU];
        #pragma unroll
        for (int k = 0; k < KU; ++k) {
            const long long g = g0 + (long long)k * blockDim.x;
            if (g <= NG) v[k] = __builtin_nontemporal_load(src + g);
        }
        #pragma unroll
        for (int k = 0; k < KU; ++k) {
            const long long g = g0 + (long long)k * blockDim.x;
            const float nx = __shfl_down(v[k].x, 1);
            const float ny = __shfl_down(v[k].y, 1);
            const float nz = __shfl_down(v[k].z, 1);
            if (g < NG) {
                f32x4 w;
                w.x = v[k].w; w.y = nx; w.z = ny; w.w = nz;
                if (lane == 63) { // g+1 lives in the next wave: patch scalar
                    w.y = __builtin_nontemporal_load(hist + 4 * (g + 1) + 0);
                    w.z = __builtin_nontemporal_load(hist + 4 * (g + 1) + 1);
                    w.w = __builtin_nontemporal_load(hist + 4 * (g + 1) + 2);
                }
                __builtin_nontemporal_store(
                    w, reinterpret_cast<f32x4*>(outh + 3 + 4 * g));
            }
        }
    }
    if (blockIdx.x == 0 && threadIdx.x == 0) {
        __builtin_nontemporal_store(hist[0], outh + 0);
        __builtin_nontemporal_store(hist[1], outh + 1);
        __builtin_nontemporal_store(hist[2], outh + 2);
        __builtin_nontemporal_store(hist[HIST_ELEMS - 1], outh + HIST_ELEMS - 1);
    }
}

// ---------------------------------------------------------------------------
// Kernel 2: one wave per sample. NT-stores the act passthrough, gathers the
// old row from the ORIGINAL history input (normal loads: gather rows are a
// tiny 8MB working set), wave-reduces squared diff -> partial[s], atomicAdd-
// scatters the EMA update (duplicates accumulate). After copy in stream order.
// ---------------------------------------------------------------------------
__global__ void update_kernel(const float* __restrict__ act,
                              const float* __restrict__ hist,
                              const int* __restrict__ samples,
                              float* __restrict__ out,
                              float* __restrict__ partial) {
    const int s    = blockIdx.x;
    const int lane = threadIdx.x; // 0..63

    const f32x4* __restrict__ arow =
        reinterpret_cast<const f32x4*>(act + (long long)s * D);
    f32x4* __restrict__ aout = reinterpret_cast<f32x4*>(out + (long long)s * D);
    const f32x4 a0 = arow[lane];
    const f32x4 a1 = arow[lane + 64];
    __builtin_nontemporal_store(a0, aout + lane);
    __builtin_nontemporal_store(a1, aout + lane + 64);

    const int id = samples[s];
    const bool active = (id > 0) && (id < MAX_ITEMS);

    float sumsq = 0.0f;
    if (active) {
        const f32x4* __restrict__ orow =
            reinterpret_cast<const f32x4*>(hist + (long long)id * D);
        float* __restrict__ newh = out + ACT_ELEMS + 1 + (long long)id * D;
        const f32x4 o0 = orow[lane];
        const f32x4 o1 = orow[lane + 64];
        {
            const float dx = a0.x - o0.x, dy = a0.y - o0.y;
            const float dz = a0.z - o0.z, dw = a0.w - o0.w;
            sumsq += dx * dx + dy * dy + dz * dz + dw * dw;
            const int e = lane * 4;
            atomicAdd(newh + e + 0, 0.1f * dx);
            atomicAdd(newh + e + 1, 0.1f * dy);
            atomicAdd(newh + e + 2, 0.1f * dz);
            atomicAdd(newh + e + 3, 0.1f * dw);
        }
        {
            const float dx = a1.x - o1.x, dy = a1.y - o1.y;
            const float dz = a1.z - o1.z, dw = a1.w - o1.w;
            sumsq += dx * dx + dy * dy + dz * dz + dw * dw;
            const int e = (lane + 64) * 4;
            atomicAdd(newh + e + 0, 0.1f * dx);
            atomicAdd(newh + e + 1, 0.1f * dy);
            atomicAdd(newh + e + 2, 0.1f * dz);
            atomicAdd(newh + e + 3, 0.1f * dw);
        }
    }
    #pragma unroll
    for (int off = 32; off; off >>= 1)
        sumsq += __shfl_down(sumsq, off);
    if (lane == 0) partial[s] = sumsq; // masked rows contribute exactly 0
}

// ---------------------------------------------------------------------------
// Kernel 3: deterministic single-block reduction of 4096 partials -> loss.
// ---------------------------------------------------------------------------
__global__ void loss_kernel(const float* __restrict__ partial,
                            const int* __restrict__ iters,
                            float* __restrict__ out) {
    __shared__ float sm[256];
    const int t = threadIdx.x;
    float s = 0.0f;
    for (int i = t; i < B; i += 256) s += partial[i];
    sm[t] = s;
    __syncthreads();
    #pragma unroll
    for (int w = 128; w; w >>= 1) {
        if (t < w) sm[t] += sm[t + w];
        __syncthreads();
    }
    if (t == 0) {
        const float it = (float)iters[0];
        const float wr = (float)(1.0 / 1000.0)   * it;
        const float cr = (float)(1.0 / 100000.0) * it;
        const float weight = 0.1f * wr / (1.0f + wr) / (1.0f + cr);
        out[ACT_ELEMS] = (sm[0] / (float)D / (float)B) * weight;
    }
}

extern "C" void kernel_launch(void* const* d_in, const int* in_sizes, int n_in,
                              void* d_out, int out_size, void* d_ws, size_t ws_size,
                              hipStream_t stream) {
    const float* act     = (const float*)d_in[0];
    const float* hist    = (const float*)d_in[1];
    const int*   samples = (const int*)d_in[2];
    const int*   iters   = (const int*)d_in[3];
    float* out     = (float*)d_out;
    float* partial = (float*)d_ws; // B*4 = 16 KiB scratch

    copy_hist_kernel<8><<<2048, 256, 0, stream>>>(hist, out);
    update_kernel<<<B, 64, 0, stream>>>(act, hist, samples, out, partial);
    loss_kernel<<<1, 256, 0, stream>>>(partial, iters, out);
}

// Round 10
// 109.842 us; speedup vs baseline: 1.6231x; 1.1367x over previous
//
#include <hip/hip_runtime.h>

#define MAX_ITEMS 100000
constexpr int B = 4096;
constexpr int D = 512;
constexpr long long ACT_ELEMS  = (long long)B * D;               // 2097152
constexpr long long HIST_ELEMS = (long long)(MAX_ITEMS + 1) * D; // 51200512
constexpr long long NG = (HIST_ELEMS - 3) / 4; // 12800127 dst-aligned float4 groups
// d_out layout: [0, ACT) activations, [ACT] loss, [ACT+1, ACT+1+HIST) new_history.
// outh = out + ACT+1 (4B-aligned); outh+3 IS 16B-aligned.

typedef float f32x4 __attribute__((ext_vector_type(4)));

// ---------------------------------------------------------------------------
// Kernel 1: history -> out[ACT+1..). dwordx4 both sides; dst group g =
// {src[g].w, src[g+1].xyz} realigned in-register via __shfl_down; lane 63
// patches with 3 scalar loads.
//   loads : NORMAL (L3-allocating; ~50% of hist stays L3-resident across
//           replays -> FETCH ~100MB. NT loads measured WORSE, R9: -15%).
//   stores: __builtin_nontemporal_store (measured best, R6: -18us vs plain;
//           sc0 sc1 nt inline-asm measured worse, R8: -20%).
// This is the measured-best configuration (R6: 108.7 us total).
// ---------------------------------------------------------------------------
template <int KU>
__global__ void copy_hist_kernel(const float* __restrict__ hist,
                                 float* __restrict__ out) {
    float* __restrict__ outh = out + ACT_ELEMS + 1;
    const float4* __restrict__ src = reinterpret_cast<const float4*>(hist);
    const int lane = threadIdx.x & 63;
    const long long chunk = (long long)blockDim.x * KU;

    for (long long c = blockIdx.x; c * chunk < NG; c += gridDim.x) {
        const long long g0 = c * chunk + threadIdx.x;
        float4 v[KU];
        #pragma unroll
        for (int k = 0; k < KU; ++k) {
            const long long g = g0 + (long long)k * blockDim.x;
            if (g <= NG) v[k] = src[g];   // group NG is valid src memory
        }
        #pragma unroll
        for (int k = 0; k < KU; ++k) {
            const long long g = g0 + (long long)k * blockDim.x;
            const float nx = __shfl_down(v[k].x, 1);
            const float ny = __shfl_down(v[k].y, 1);
            const float nz = __shfl_down(v[k].z, 1);
            if (g < NG) {
                f32x4 w;
                w.x = v[k].w; w.y = nx; w.z = ny; w.w = nz;
                if (lane == 63) { // g+1 lives in the next wave: patch scalar
                    w.y = hist[4 * (g + 1) + 0];
                    w.z = hist[4 * (g + 1) + 1];
                    w.w = hist[4 * (g + 1) + 2];
                }
                __builtin_nontemporal_store(
                    w, reinterpret_cast<f32x4*>(outh + 3 + 4 * g));
            }
        }
    }
    if (blockIdx.x == 0 && threadIdx.x == 0) {
        __builtin_nontemporal_store(hist[0], outh + 0);
        __builtin_nontemporal_store(hist[1], outh + 1);
        __builtin_nontemporal_store(hist[2], outh + 2);
        __builtin_nontemporal_store(hist[HIST_ELEMS - 1], outh + HIST_ELEMS - 1);
    }
}

// ---------------------------------------------------------------------------
// Kernel 2: one wave per sample. NT-stores the act passthrough, gathers the
// old row from the ORIGINAL history input, wave-reduces squared diff ->
// partial[s], atomicAdd-scatters the EMA update into new_history (duplicate
// ids must accumulate). Runs after copy_hist in stream order.
// ---------------------------------------------------------------------------
__global__ void update_kernel(const float* __restrict__ act,
                              const float* __restrict__ hist,
                              const int* __restrict__ samples,
                              float* __restrict__ out,
                              float* __restrict__ partial) {
    const int s    = blockIdx.x;
    const int lane = threadIdx.x; // 0..63

    const f32x4* __restrict__ arow =
        reinterpret_cast<const f32x4*>(act + (long long)s * D);
    f32x4* __restrict__ aout = reinterpret_cast<f32x4*>(out + (long long)s * D);
    const f32x4 a0 = arow[lane];
    const f32x4 a1 = arow[lane + 64];
    __builtin_nontemporal_store(a0, aout + lane);
    __builtin_nontemporal_store(a1, aout + lane + 64);

    const int id = samples[s];
    const bool active = (id > 0) && (id < MAX_ITEMS);

    float sumsq = 0.0f;
    if (active) {
        const f32x4* __restrict__ orow =
            reinterpret_cast<const f32x4*>(hist + (long long)id * D);
        float* __restrict__ newh = out + ACT_ELEMS + 1 + (long long)id * D;
        const f32x4 o0 = orow[lane];
        const f32x4 o1 = orow[lane + 64];
        {
            const float dx = a0.x - o0.x, dy = a0.y - o0.y;
            const float dz = a0.z - o0.z, dw = a0.w - o0.w;
            sumsq += dx * dx + dy * dy + dz * dz + dw * dw;
            const int e = lane * 4;
            atomicAdd(newh + e + 0, 0.1f * dx);
            atomicAdd(newh + e + 1, 0.1f * dy);
            atomicAdd(newh + e + 2, 0.1f * dz);
            atomicAdd(newh + e + 3, 0.1f * dw);
        }
        {
            const float dx = a1.x - o1.x, dy = a1.y - o1.y;
            const float dz = a1.z - o1.z, dw = a1.w - o1.w;
            sumsq += dx * dx + dy * dy + dz * dz + dw * dw;
            const int e = (lane + 64) * 4;
            atomicAdd(newh + e + 0, 0.1f * dx);
            atomicAdd(newh + e + 1, 0.1f * dy);
            atomicAdd(newh + e + 2, 0.1f * dz);
            atomicAdd(newh + e + 3, 0.1f * dw);
        }
    }
    #pragma unroll
    for (int off = 32; off; off >>= 1)
        sumsq += __shfl_down(sumsq, off);
    if (lane == 0) partial[s] = sumsq; // masked rows contribute exactly 0
}

// ---------------------------------------------------------------------------
// Kernel 3: deterministic single-block reduction of 4096 partials -> loss.
// ---------------------------------------------------------------------------
__global__ void loss_kernel(const float* __restrict__ partial,
                            const int* __restrict__ iters,
                            float* __restrict__ out) {
    __shared__ float sm[256];
    const int t = threadIdx.x;
    float s = 0.0f;
    for (int i = t; i < B; i += 256) s += partial[i];
    sm[t] = s;
    __syncthreads();
    #pragma unroll
    for (int w = 128; w; w >>= 1) {
        if (t < w) sm[t] += sm[t + w];
        __syncthreads();
    }
    if (t == 0) {
        const float it = (float)iters[0];
        const float wr = (float)(1.0 / 1000.0)   * it;
        const float cr = (float)(1.0 / 100000.0) * it;
        const float weight = 0.1f * wr / (1.0f + wr) / (1.0f + cr);
        out[ACT_ELEMS] = (sm[0] / (float)D / (float)B) * weight;
    }
}

extern "C" void kernel_launch(void* const* d_in, const int* in_sizes, int n_in,
                              void* d_out, int out_size, void* d_ws, size_t ws_size,
                              hipStream_t stream) {
    const float* act     = (const float*)d_in[0];
    const float* hist    = (const float*)d_in[1];
    const int*   samples = (const int*)d_in[2];
    const int*   iters   = (const int*)d_in[3];
    float* out     = (float*)d_out;
    float* partial = (float*)d_ws; // B*4 = 16 KiB scratch

    copy_hist_kernel<8><<<2048, 256, 0, stream>>>(hist, out);
    update_kernel<<<B, 64, 0, stream>>>(act, hist, samples, out, partial);
    loss_kernel<<<1, 256, 0, stream>>>(partial, iters, out);
}